// Round 1
// baseline (80256.226 us; speedup 1.0000x reference)
//
#include <hip/hip_runtime.h>

#define DI __device__ __forceinline__

typedef __bf16  bf16x8 __attribute__((ext_vector_type(8)));
typedef float   f32x4  __attribute__((ext_vector_type(4)));
typedef unsigned short u16;
typedef unsigned int   u32;

DI u16 f2bf(float f){ u32 u = __float_as_uint(f); u32 r = 0x7fffu + ((u>>16)&1u); return (u16)((u + r) >> 16); }
DI float bf2f(u16 h){ return __uint_as_float(((u32)h)<<16); }

union U16x8 { u16 u[8]; uint4 v; };

#define MFMA(a,b,c) __builtin_amdgcn_mfma_f32_16x16x32_bf16((a),(b),(c),0,0,0)

// ---- problem constants
#define Tn 512
#define Bn 2048
#define Fn 16
#define Hn 512
#define NK32 16   // 512/32 k-subtiles

// ---- workspace layout (bytes)
#define OFF_WH0  0ull
#define OFF_WI1  3145728ull
#define OFF_WH1  6291456ull
#define OFF_WI0  9437184ull
#define OFF_H0F  9633792ull
#define OFF_H1F  18022400ull
#define OFF_H0HI 26411008ull
#define OFF_H0LO 30605312ull
#define OFF_H1HI 34799616ull
#define OFF_H1LO 38993920ull
// total 43188224 bytes

// =====================================================================
// Prep: fp32 [3H x K] weights -> frag-linear bf16 hi/lo subtile pairs.
// Subtile (16j x 32k) = 64 lanes x 16B, lane = (j&15) + ((k>>3)&3)*16,
// byte-in-lane = (k&7)*2.  Pair = {hi 1KB, lo 1KB}.
// pairidx = (g*32 + (j>>4))*NK + k32
// =====================================================================
__global__ __launch_bounds__(256) void prep_w(const float* __restrict__ w0,
                                              const float* __restrict__ w1,
                                              const float* __restrict__ w2,
                                              u16* __restrict__ dst){
  int tid = blockIdx.x*256 + threadIdx.x;        // 294912 total
  int p = tid / 98304, rem = tid % 98304;        // part: 0=WH0 1=WI1 2=WH1
  int g = rem / 32768, rem2 = rem % 32768;
  int j = rem2 / 64,   k8 = rem2 % 64;           // k = k8*8
  const float* src = (p==0) ? w0 : ((p==1) ? w1 : w2);
  const float* s = src + (size_t)(g*Hn + j)*Hn + k8*8;
  U16x8 hi, lo;
#pragma unroll
  for (int i=0;i<8;++i){ float v = s[i]; u16 h = f2bf(v); hi.u[i]=h; lo.u[i]=f2bf(v - bf2f(h)); }
  size_t pairidx = (size_t)(g*32 + (j>>4))*16 + (k8>>2);
  u16* d = dst + (size_t)p*1572864 + pairidx*1024 + (size_t)((j&15) + (k8&3)*16)*8;
  *(uint4*)d = hi.v;
  *(uint4*)(d + 512) = lo.v;
}

// W_ih0: [3H x 16] padded to K=32 (upper k zeros), NK=1
__global__ __launch_bounds__(256) void prep_wi0(const float* __restrict__ w,
                                                u16* __restrict__ dst){
  int tid = blockIdx.x*256 + threadIdx.x;        // 6144 total
  int g = tid / 2048, j = (tid % 2048) >> 2, k8 = tid & 3;
  U16x8 hi, lo;
  if (k8 < 2){
    const float* s = w + (size_t)(g*Hn + j)*Fn + k8*8;
#pragma unroll
    for (int i=0;i<8;++i){ float v = s[i]; u16 h = f2bf(v); hi.u[i]=h; lo.u[i]=f2bf(v - bf2f(h)); }
  } else {
#pragma unroll
    for (int i=0;i<8;++i){ hi.u[i]=0; lo.u[i]=0; }
  }
  size_t pairidx = (size_t)(g*32 + (j>>4));
  u16* d = dst + pairidx*1024 + (size_t)((j&15) + k8*16)*8;
  *(uint4*)d = hi.v;
  *(uint4*)(d + 512) = lo.v;
}

// zero parity-0 state buffers (f32 + hi/lo)
__global__ __launch_bounds__(256) void zero_ws(char* __restrict__ ws){
  int tid = blockIdx.x*256 + threadIdx.x;        // 1,048,576 x 16B
  uint4 z = {0u,0u,0u,0u};
  size_t o;
  if      (tid < 262144) o = OFF_H0F  + (size_t)tid*16;
  else if (tid < 524288) o = OFF_H1F  + (size_t)(tid-262144)*16;
  else if (tid < 655360) o = OFF_H0HI + (size_t)(tid-524288)*16;
  else if (tid < 786432) o = OFF_H0LO + (size_t)(tid-655360)*16;
  else if (tid < 917504) o = OFF_H1HI + (size_t)(tid-786432)*16;
  else                   o = OFF_H1LO + (size_t)(tid-917504)*16;
  *(uint4*)(ws + o) = z;
}

// =====================================================================
// Fused GEMM + GRU-cell step kernel.
// Grid 512 = 16 M-tiles(128 rows) x 32 j-tiles(16 cols). Block 256 (4 waves).
// Wave w owns rows [w*32, w*32+32): 2 m-frags of 16 rows.
// acc[m][0]=i_r+h_r  acc[m][1]=i_z+h_z  acc[m][2]=i_n  acc[m][3]=h_n
// K loop: i-stream (x or h0new) then h-stream (own state), 32 k per step.
// LDS: 2 x { A_hi 8KB | A_lo 8KB | W 6KB } + X 8KB = 53248 B
// =====================================================================
template<int IS_L0>
__global__ __launch_bounds__(256, 2) void gru_step(
    const u16* __restrict__ Wi, const u16* __restrict__ Wh,
    const float* __restrict__ xsrc,
    const u16* __restrict__ Ai_hi, const u16* __restrict__ Ai_lo,
    const u16* __restrict__ Ah_hi, const u16* __restrict__ Ah_lo,
    const float* __restrict__ hprev,
    const float* __restrict__ b_ih, const float* __restrict__ b_hh,
    float* __restrict__ hout_f, u16* __restrict__ hout_hi, u16* __restrict__ hout_lo)
{
  constexpr int NI = IS_L0 ? 1 : 16;     // i-stream K-steps
  constexpr int NT = IS_L0 ? 17 : 32;    // total K-steps
  __shared__ __align__(16) char smem[53248];
  const int tid  = threadIdx.x;
  const int lane = tid & 63, wv = tid >> 6;
  const int mt = blockIdx.x >> 5, jt = blockIdx.x & 31;

  f32x4 acc[2][4];
#pragma unroll
  for (int m=0;m<2;++m)
#pragma unroll
    for (int o=0;o<4;++o){ f32x4 z = {0.f,0.f,0.f,0.f}; acc[m][o] = z; }

  // ---- L0: prestage x tile (K=16 real, padded to 32) as bf16 frag-linear
  if (IS_L0){
    int b_loc = tid >> 1, kh = tid & 1;
    const float* xs = xsrc + (size_t)(mt*128 + b_loc)*Fn + kh*8;
    U16x8 u;
#pragma unroll
    for (int i=0;i<8;++i) u.u[i] = f2bf(xs[i]);
    char* dst = smem + 45056 + (b_loc>>4)*1024 + (size_t)((b_loc&15) + kh*16)*16;
    *(uint4*)dst = u.v;
    uint4 z = {0u,0u,0u,0u};
    *(uint4*)(dst + 512) = z;      // k 16..31 zero pad
  }

  uint4 sA[4]; uint4 sW[2];

  auto stage_load = [&](int t){
    bool ish = (t >= NI);
    if (!(IS_L0 && t==0)){
      int k32 = ish ? (t - NI) : t;
      const u16* ahi = ish ? Ah_hi : Ai_hi;
      const u16* alo = ish ? Ah_lo : Ai_lo;
#pragma unroll
      for (int ii=0; ii<2; ++ii){
        int sub = ii*4 + wv;
        size_t go = ((size_t)((mt*8+sub)*NK32 + k32))*512 + (size_t)lane*8;
        sA[ii]   = *(const uint4*)(ahi + go);
        sA[2+ii] = *(const uint4*)(alo + go);
      }
    }
    {
      const u16* w = ish ? Wh : Wi;
      int nk   = (IS_L0 && !ish) ? 1 : NK32;
      int k32w = ish ? (t - NI) : (IS_L0 ? 0 : t);
#pragma unroll
      for (int ii=0; ii<2; ++ii){
        int task = ii*4 + wv;
        if (task < 6){
          int g = task>>1, hl = task&1;
          size_t go = ((size_t)((g*32 + jt)*nk + k32w))*1024 + (size_t)hl*512 + (size_t)lane*8;
          sW[ii] = *(const uint4*)(w + go);
        }
      }
    }
  };

  auto stage_write = [&](int t, int bn){
    char* buf = smem + bn*22528;
    if (!(IS_L0 && t==0)){
#pragma unroll
      for (int ii=0; ii<2; ++ii){
        int sub = ii*4 + wv;
        *(uint4*)(buf +        sub*1024 + lane*16) = sA[ii];
        *(uint4*)(buf + 8192 + sub*1024 + lane*16) = sA[2+ii];
      }
    }
#pragma unroll
    for (int ii=0; ii<2; ++ii){
      int task = ii*4 + wv;
      if (task < 6) *(uint4*)(buf + 16384 + task*1024 + lane*16) = sW[ii];
    }
  };

  auto compute = [&](int t, int bn){
    const char* buf = smem + bn*22528;
    bf16x8 w[3][2];
#pragma unroll
    for (int g=0; g<3; ++g)
#pragma unroll
      for (int hl=0; hl<2; ++hl)
        w[g][hl] = *(const bf16x8*)(buf + 16384 + (g*2+hl)*1024 + lane*16);
    bool ish = (t >= NI);
    if (IS_L0 && t==0){
#pragma unroll
      for (int m=0;m<2;++m){
        bf16x8 ax = *(const bf16x8*)(smem + 45056 + (wv*2+m)*1024 + lane*16);
        acc[m][0] = MFMA(ax, w[0][0], acc[m][0]); acc[m][0] = MFMA(ax, w[0][1], acc[m][0]);
        acc[m][1] = MFMA(ax, w[1][0], acc[m][1]); acc[m][1] = MFMA(ax, w[1][1], acc[m][1]);
        acc[m][2] = MFMA(ax, w[2][0], acc[m][2]); acc[m][2] = MFMA(ax, w[2][1], acc[m][2]);
      }
    } else {
#pragma unroll
      for (int m=0;m<2;++m){
        bf16x8 ah = *(const bf16x8*)(buf +        (wv*2+m)*1024 + lane*16);
        bf16x8 al = *(const bf16x8*)(buf + 8192 + (wv*2+m)*1024 + lane*16);
        acc[m][0] = MFMA(ah, w[0][0], acc[m][0]);
        acc[m][0] = MFMA(ah, w[0][1], acc[m][0]);
        acc[m][0] = MFMA(al, w[0][0], acc[m][0]);
        acc[m][1] = MFMA(ah, w[1][0], acc[m][1]);
        acc[m][1] = MFMA(ah, w[1][1], acc[m][1]);
        acc[m][1] = MFMA(al, w[1][0], acc[m][1]);
        if (!ish){
          acc[m][2] = MFMA(ah, w[2][0], acc[m][2]);
          acc[m][2] = MFMA(ah, w[2][1], acc[m][2]);
          acc[m][2] = MFMA(al, w[2][0], acc[m][2]);
        } else {
          acc[m][3] = MFMA(ah, w[2][0], acc[m][3]);
          acc[m][3] = MFMA(ah, w[2][1], acc[m][3]);
          acc[m][3] = MFMA(al, w[2][0], acc[m][3]);
        }
      }
    }
  };

  // ---- pipelined K loop: load(t+1) -> mfma(t) -> ds_write(t+1) -> barrier
  stage_load(0);
  stage_write(0, 0);
  __syncthreads();
#pragma unroll 2
  for (int t=0; t<NT; ++t){
    if (t+1 < NT) stage_load(t+1);
    compute(t, t&1);
    if (t+1 < NT) stage_write(t+1, (t+1)&1);
    __syncthreads();
  }

  // ---- GRU epilogue (elementwise on C-fragments: col=lane&15, row=(lane>>4)*4+r)
  const int col = lane & 15, rg = lane >> 4;
  const int j = jt*16 + col;
  const float bir = b_ih[j], biz = b_ih[Hn + j], bin = b_ih[2*Hn + j];
  const float bhr = b_hh[j], bhz = b_hh[Hn + j], bhn = b_hh[2*Hn + j];
#pragma unroll
  for (int m=0;m<2;++m){
    int brow = mt*128 + wv*32 + m*16 + rg*4;
#pragma unroll
    for (int r=0;r<4;++r){
      int b = brow + r;
      float pr  = acc[m][0][r] + bir + bhr;
      float pz  = acc[m][1][r] + biz + bhz;
      float pin = acc[m][2][r] + bin;
      float phn = acc[m][3][r] + bhn;
      float rgt = 1.f/(1.f + __expf(-pr));
      float zgt = 1.f/(1.f + __expf(-pz));
      float e2  = __expf(2.f*(pin + rgt*phn));
      float nn  = 1.f - 2.f/(e2 + 1.f);           // tanh, overflow-safe
      float hv  = hprev[(size_t)b*Hn + j];
      float hnv = (1.f - zgt)*nn + zgt*hv;
      hout_f[(size_t)b*Hn + j] = hnv;
      u16 hi = f2bf(hnv);
      u16 lo = f2bf(hnv - bf2f(hi));
      size_t fo = ((size_t)(b>>4)*NK32 + (j>>5))*512 + (size_t)((b&15) + ((j>>3)&3)*16)*8 + (j&7);
      hout_hi[fo] = hi; hout_lo[fo] = lo;
    }
  }
}

// final projection: out[b][o] = h1[b,:] . Wout[o,:] + bout[o]   (fp32 exact)
__global__ __launch_bounds__(64) void outproj(const float* __restrict__ h1,
                                              const float* __restrict__ Wout,
                                              const float* __restrict__ bout,
                                              float* __restrict__ out){
  int b = blockIdx.x, l = threadIdx.x;
  float a[8] = {0.f,0.f,0.f,0.f,0.f,0.f,0.f,0.f};
  for (int jj = l; jj < Hn; jj += 64){
    float hv = h1[(size_t)b*Hn + jj];
#pragma unroll
    for (int o=0;o<8;++o) a[o] += hv * Wout[o*Hn + jj];
  }
#pragma unroll
  for (int o=0;o<8;++o){
#pragma unroll
    for (int off=32; off; off>>=1) a[o] += __shfl_xor(a[o], off);
  }
  if (l == 0){
#pragma unroll
    for (int o=0;o<8;++o) out[b*8+o] = a[o] + bout[o];
  }
}

extern "C" void kernel_launch(void* const* d_in, const int* in_sizes, int n_in,
                              void* d_out, int out_size, void* d_ws, size_t ws_size,
                              hipStream_t stream){
  (void)in_sizes; (void)n_in; (void)out_size; (void)ws_size;
  const float* x    = (const float*)d_in[0];
  const float* Wih0 = (const float*)d_in[1];
  const float* Whh0 = (const float*)d_in[2];
  const float* bih0 = (const float*)d_in[3];
  const float* bhh0 = (const float*)d_in[4];
  const float* Wih1 = (const float*)d_in[5];
  const float* Whh1 = (const float*)d_in[6];
  const float* bih1 = (const float*)d_in[7];
  const float* bhh1 = (const float*)d_in[8];
  const float* Wout = (const float*)d_in[9];
  const float* bout = (const float*)d_in[10];
  char* ws = (char*)d_ws;

  u16* WH0 = (u16*)(ws + OFF_WH0);
  const u16* WI1 = (const u16*)(ws + OFF_WI1);
  const u16* WH1 = (const u16*)(ws + OFF_WH1);
  const u16* WI0 = (const u16*)(ws + OFF_WI0);
  float* H0F = (float*)(ws + OFF_H0F);
  float* H1F = (float*)(ws + OFF_H1F);
  u16 *H0HI = (u16*)(ws + OFF_H0HI), *H0LO = (u16*)(ws + OFF_H0LO);
  u16 *H1HI = (u16*)(ws + OFF_H1HI), *H1LO = (u16*)(ws + OFF_H1LO);

  prep_w  <<<1152, 256, 0, stream>>>(Whh0, Wih1, Whh1, WH0);
  prep_wi0<<<  24, 256, 0, stream>>>(Wih0, (u16*)(ws + OFF_WI0));
  zero_ws <<<4096, 256, 0, stream>>>(ws);

  for (int s = 0; s < Tn; ++s){
    int rp = s & 1, wp = rp ^ 1;
    gru_step<1><<<512, 256, 0, stream>>>(
        WI0, (const u16*)WH0,
        x + (size_t)s*Bn*Fn,
        nullptr, nullptr,
        H0HI + (size_t)rp*1048576, H0LO + (size_t)rp*1048576,
        H0F  + (size_t)rp*1048576,
        bih0, bhh0,
        H0F  + (size_t)wp*1048576, H0HI + (size_t)wp*1048576, H0LO + (size_t)wp*1048576);
    gru_step<0><<<512, 256, 0, stream>>>(
        WI1, WH1,
        nullptr,
        H0HI + (size_t)wp*1048576, H0LO + (size_t)wp*1048576,
        H1HI + (size_t)rp*1048576, H1LO + (size_t)rp*1048576,
        H1F  + (size_t)rp*1048576,
        bih1, bhh1,
        H1F  + (size_t)wp*1048576, H1HI + (size_t)wp*1048576, H1LO + (size_t)wp*1048576);
  }

  outproj<<<2048, 64, 0, stream>>>(H1F, Wout, bout, (float*)d_out);
}

// Round 2
// 21192.632 us; speedup vs baseline: 3.7870x; 3.7870x over previous
//
#include <hip/hip_runtime.h>

#define DI __device__ __forceinline__

typedef __bf16  bf16x8 __attribute__((ext_vector_type(8)));
typedef float   f32x4  __attribute__((ext_vector_type(4)));
typedef unsigned short u16;
typedef unsigned int   u32;

DI u16 f2bf(float f){ u32 u = __float_as_uint(f); u32 r = 0x7fffu + ((u>>16)&1u); return (u16)((u + r) >> 16); }
DI float bf2f(u16 h){ return __uint_as_float(((u32)h)<<16); }

union U16x8 { u16 u[8]; uint4 v; };

#define MFMA(a,b,c) __builtin_amdgcn_mfma_f32_16x16x32_bf16((a),(b),(c),0,0,0)

// async global->LDS, 16B per lane. LDS dest = wave-uniform base (+lane*16 by HW).
DI void gload16(const void* g, void* l){
  __builtin_amdgcn_global_load_lds((const __attribute__((address_space(1))) u32*)g,
                                   (__attribute__((address_space(3))) u32*)l, 16, 0, 0);
}

// ---- problem constants
#define Tn 512
#define Bn 2048
#define Fn 16
#define Hn 512
#define NK32 16   // 512/32 k-subtiles

// ---- workspace layout (bytes)
#define OFF_WH0  0ull
#define OFF_WI1  3145728ull
#define OFF_WH1  6291456ull
#define OFF_WI0  9437184ull
#define OFF_H0HI 9633792ull
#define OFF_H0LO 13828096ull
#define OFF_H1HI 18022400ull
#define OFF_H1LO 22216704ull
// total 26411008 bytes

// =====================================================================
// Prep: fp32 [3H x K] weights -> frag-linear bf16 hi/lo subtile pairs.
// Subtile (16j x 32k) = 64 lanes x 16B, lane = (j&15) + ((k>>3)&3)*16,
// byte-in-lane = (k&7)*2.  Pair = {hi 1KB, lo 1KB}.
// pairidx = (g*32 + (j>>4))*NK + k32
// =====================================================================
__global__ __launch_bounds__(256) void prep_w(const float* __restrict__ w0,
                                              const float* __restrict__ w1,
                                              const float* __restrict__ w2,
                                              u16* __restrict__ dst){
  int tid = blockIdx.x*256 + threadIdx.x;        // 294912 total
  int p = tid / 98304, rem = tid % 98304;        // part: 0=WH0 1=WI1 2=WH1
  int g = rem / 32768, rem2 = rem % 32768;
  int j = rem2 / 64,   k8 = rem2 % 64;           // k = k8*8
  const float* src = (p==0) ? w0 : ((p==1) ? w1 : w2);
  const float* s = src + (size_t)(g*Hn + j)*Hn + k8*8;
  U16x8 hi, lo;
#pragma unroll
  for (int i=0;i<8;++i){ float v = s[i]; u16 h = f2bf(v); hi.u[i]=h; lo.u[i]=f2bf(v - bf2f(h)); }
  size_t pairidx = (size_t)(g*32 + (j>>4))*16 + (k8>>2);
  u16* d = dst + (size_t)p*1572864 + pairidx*1024 + (size_t)((j&15) + (k8&3)*16)*8;
  *(uint4*)d = hi.v;
  *(uint4*)(d + 512) = lo.v;
}

// W_ih0: [3H x 16] padded to K=32 (upper k zeros), NK=1
__global__ __launch_bounds__(256) void prep_wi0(const float* __restrict__ w,
                                                u16* __restrict__ dst){
  int tid = blockIdx.x*256 + threadIdx.x;        // 6144 total
  int g = tid / 2048, j = (tid % 2048) >> 2, k8 = tid & 3;
  U16x8 hi, lo;
  if (k8 < 2){
    const float* s = w + (size_t)(g*Hn + j)*Fn + k8*8;
#pragma unroll
    for (int i=0;i<8;++i){ float v = s[i]; u16 h = f2bf(v); hi.u[i]=h; lo.u[i]=f2bf(v - bf2f(h)); }
  } else {
#pragma unroll
    for (int i=0;i<8;++i){ hi.u[i]=0; lo.u[i]=0; }
  }
  size_t pairidx = (size_t)(g*32 + (j>>4));
  u16* d = dst + pairidx*1024 + (size_t)((j&15) + k8*16)*8;
  *(uint4*)d = hi.v;
  *(uint4*)(d + 512) = lo.v;
}

// zero parity-0 hi/lo state buffers
__global__ __launch_bounds__(256) void zero_ws(char* __restrict__ ws){
  int tid = blockIdx.x*256 + threadIdx.x;        // 524288 x 16B
  uint4 z = {0u,0u,0u,0u};
  int region = tid >> 17;                        // 131072 x 16B = 2MB each
  int off = tid & 131071;
  size_t base = (region==0) ? OFF_H0HI : (region==1) ? OFF_H0LO
              : (region==2) ? OFF_H1HI : OFF_H1LO;
  *(uint4*)(ws + base + (size_t)off*16) = z;
}

// =====================================================================
// Fused GEMM + GRU-cell step kernel.
// Grid 512. XCD-pinned decode: xcd=blockIdx&7 owns jt in [xcd*4, xcd*4+4)
// so each XCD's W slice (0.78MB/layer) is L2-resident and A gets 4-fold
// L2 reuse. Block 256 (4 waves), wave w owns rows [w*32, w*32+32).
// acc[m][0]=i_r+h_r  acc[m][1]=i_z+h_z  acc[m][2]=i_n  acc[m][3]=h_n
// LDS: 2 x { A_hi 8KB | A_lo 8KB | W 6KB } + X 8KB = 53248 B
// Staging via global_load_lds(16B): LDS layout is lane-linear by design.
// =====================================================================
template<int IS_L0>
__global__ __launch_bounds__(256, 2) void gru_step(
    const u16* __restrict__ Wi, const u16* __restrict__ Wh,
    const float* __restrict__ xsrc,
    const u16* __restrict__ Ai_hi, const u16* __restrict__ Ai_lo,
    const u16* __restrict__ Ah_hi, const u16* __restrict__ Ah_lo,
    const float* __restrict__ b_ih, const float* __restrict__ b_hh,
    u16* __restrict__ hout_hi, u16* __restrict__ hout_lo)
{
  constexpr int NI = IS_L0 ? 1 : 16;     // i-stream K-steps
  constexpr int NT = IS_L0 ? 17 : 32;    // total K-steps
  __shared__ __align__(16) char smem[53248];
  const int tid  = threadIdx.x;
  const int lane = tid & 63, wv = tid >> 6;
  const int xcd = blockIdx.x & 7, idx2 = blockIdx.x >> 3;
  const int mt = idx2 >> 2, jt = xcd*4 + (idx2 & 3);

  f32x4 acc[2][4];
#pragma unroll
  for (int m=0;m<2;++m)
#pragma unroll
    for (int o=0;o<4;++o){ f32x4 z = {0.f,0.f,0.f,0.f}; acc[m][o] = z; }

  // ---- L0: prestage x tile (K=16 real, padded to 32) as bf16 frag-linear
  if (IS_L0){
    int b_loc = tid >> 1, kh = tid & 1;
    const float* xs = xsrc + (size_t)(mt*128 + b_loc)*Fn + kh*8;
    U16x8 u;
#pragma unroll
    for (int i=0;i<8;++i) u.u[i] = f2bf(xs[i]);
    char* dst = smem + 45056 + (b_loc>>4)*1024 + (size_t)((b_loc&15) + kh*16)*16;
    *(uint4*)dst = u.v;
    uint4 z = {0u,0u,0u,0u};
    *(uint4*)(dst + 512) = z;      // k 16..31 zero pad
  }

  auto issue = [&](int t, int bn){
    char* buf = smem + bn*22528;
    bool ish = (t >= NI);
    if (!(IS_L0 && t==0)){
      int k32 = ish ? (t - NI) : t;
      const u16* ahi = ish ? Ah_hi : Ai_hi;
      const u16* alo = ish ? Ah_lo : Ai_lo;
#pragma unroll
      for (int ii=0; ii<2; ++ii){
        int sub = ii*4 + wv;
        size_t go = ((size_t)((mt*8+sub)*NK32 + k32))*512 + (size_t)lane*8;
        gload16(ahi + go, buf +        sub*1024);
        gload16(alo + go, buf + 8192 + sub*1024);
      }
    }
    {
      const u16* w = ish ? Wh : Wi;
      int nk   = (IS_L0 && !ish) ? 1 : NK32;
      int k32w = ish ? (t - NI) : (IS_L0 ? 0 : t);
#pragma unroll
      for (int ii=0; ii<2; ++ii){
        int task = ii*4 + wv;
        if (task < 6){
          int g = task>>1, hl = task&1;
          size_t go = ((size_t)((g*32 + jt)*nk + k32w))*1024 + (size_t)hl*512 + (size_t)lane*8;
          gload16(w + go, buf + 16384 + task*1024);
        }
      }
    }
  };

  auto compute = [&](int t, int bn){
    const char* buf = smem + bn*22528;
    bf16x8 w[3][2];
#pragma unroll
    for (int g=0; g<3; ++g)
#pragma unroll
      for (int hl=0; hl<2; ++hl)
        w[g][hl] = *(const bf16x8*)(buf + 16384 + (g*2+hl)*1024 + lane*16);
    bool ish = (t >= NI);
    if (IS_L0 && t==0){
#pragma unroll
      for (int m=0;m<2;++m){
        bf16x8 ax = *(const bf16x8*)(smem + 45056 + (wv*2+m)*1024 + lane*16);
        acc[m][0] = MFMA(ax, w[0][0], acc[m][0]); acc[m][0] = MFMA(ax, w[0][1], acc[m][0]);
        acc[m][1] = MFMA(ax, w[1][0], acc[m][1]); acc[m][1] = MFMA(ax, w[1][1], acc[m][1]);
        acc[m][2] = MFMA(ax, w[2][0], acc[m][2]); acc[m][2] = MFMA(ax, w[2][1], acc[m][2]);
      }
    } else {
#pragma unroll
      for (int m=0;m<2;++m){
        bf16x8 ah = *(const bf16x8*)(buf +        (wv*2+m)*1024 + lane*16);
        bf16x8 al = *(const bf16x8*)(buf + 8192 + (wv*2+m)*1024 + lane*16);
        acc[m][0] = MFMA(ah, w[0][0], acc[m][0]);
        acc[m][0] = MFMA(ah, w[0][1], acc[m][0]);
        acc[m][0] = MFMA(al, w[0][0], acc[m][0]);
        acc[m][1] = MFMA(ah, w[1][0], acc[m][1]);
        acc[m][1] = MFMA(ah, w[1][1], acc[m][1]);
        acc[m][1] = MFMA(al, w[1][0], acc[m][1]);
        if (!ish){
          acc[m][2] = MFMA(ah, w[2][0], acc[m][2]);
          acc[m][2] = MFMA(ah, w[2][1], acc[m][2]);
          acc[m][2] = MFMA(al, w[2][0], acc[m][2]);
        } else {
          acc[m][3] = MFMA(ah, w[2][0], acc[m][3]);
          acc[m][3] = MFMA(ah, w[2][1], acc[m][3]);
          acc[m][3] = MFMA(al, w[2][0], acc[m][3]);
        }
      }
    }
  };

  // ---- 2-phase pipelined K loop (T3 minimal recipe):
  // issue(t+1) -> mfma(t) -> barrier (drains vmcnt -> buf[t+1] ready)
  issue(0, 0);
  __syncthreads();
#pragma unroll 2
  for (int t=0; t<NT; ++t){
    if (t+1 < NT) issue(t+1, (t+1)&1);
    compute(t, t&1);
    __syncthreads();
  }

  // ---- GRU epilogue (C-fragment map: col=lane&15, row=(lane>>4)*4+r)
  const int col = lane & 15, rg = lane >> 4;
  const int j = jt*16 + col;
  const float bir = b_ih[j], biz = b_ih[Hn + j], bin = b_ih[2*Hn + j];
  const float bhr = b_hh[j], bhz = b_hh[Hn + j], bhn = b_hh[2*Hn + j];
#pragma unroll
  for (int m=0;m<2;++m){
    int brow = mt*128 + wv*32 + m*16 + rg*4;
#pragma unroll
    for (int r=0;r<4;++r){
      int b = brow + r;
      float pr  = acc[m][0][r] + bir + bhr;
      float pz  = acc[m][1][r] + biz + bhz;
      float pin = acc[m][2][r] + bin;
      float phn = acc[m][3][r] + bhn;
      float rgt = 1.f/(1.f + __expf(-pr));
      float zgt = 1.f/(1.f + __expf(-pz));
      float e2  = __expf(2.f*(pin + rgt*phn));
      float nn  = 1.f - 2.f/(e2 + 1.f);           // tanh, overflow-safe
      size_t fo = ((size_t)(b>>4)*NK32 + (j>>5))*512 + (size_t)((b&15) + ((j>>3)&3)*16)*8 + (j&7);
      float hv  = bf2f(Ah_hi[fo]) + bf2f(Ah_lo[fo]);   // h_prev reconstructed
      float hnv = (1.f - zgt)*nn + zgt*hv;
      u16 hi = f2bf(hnv);
      u16 lo = f2bf(hnv - bf2f(hi));
      hout_hi[fo] = hi; hout_lo[fo] = lo;
    }
  }
}

// final projection: out[b][o] = h1[b,:] . Wout[o,:] + bout[o]
__global__ __launch_bounds__(64) void outproj(const u16* __restrict__ h1hi,
                                              const u16* __restrict__ h1lo,
                                              const float* __restrict__ Wout,
                                              const float* __restrict__ bout,
                                              float* __restrict__ out){
  int b = blockIdx.x, l = threadIdx.x;
  float a[8] = {0.f,0.f,0.f,0.f,0.f,0.f,0.f,0.f};
  for (int jj = l; jj < Hn; jj += 64){
    size_t fo = ((size_t)(b>>4)*NK32 + (jj>>5))*512 + (size_t)((b&15) + ((jj>>3)&3)*16)*8 + (jj&7);
    float hv = bf2f(h1hi[fo]) + bf2f(h1lo[fo]);
#pragma unroll
    for (int o=0;o<8;++o) a[o] += hv * Wout[o*Hn + jj];
  }
#pragma unroll
  for (int o=0;o<8;++o){
#pragma unroll
    for (int off=32; off; off>>=1) a[o] += __shfl_xor(a[o], off);
  }
  if (l == 0){
#pragma unroll
    for (int o=0;o<8;++o) out[b*8+o] = a[o] + bout[o];
  }
}

extern "C" void kernel_launch(void* const* d_in, const int* in_sizes, int n_in,
                              void* d_out, int out_size, void* d_ws, size_t ws_size,
                              hipStream_t stream){
  (void)in_sizes; (void)n_in; (void)out_size; (void)ws_size;
  const float* x    = (const float*)d_in[0];
  const float* Wih0 = (const float*)d_in[1];
  const float* Whh0 = (const float*)d_in[2];
  const float* bih0 = (const float*)d_in[3];
  const float* bhh0 = (const float*)d_in[4];
  const float* Wih1 = (const float*)d_in[5];
  const float* Whh1 = (const float*)d_in[6];
  const float* bih1 = (const float*)d_in[7];
  const float* bhh1 = (const float*)d_in[8];
  const float* Wout = (const float*)d_in[9];
  const float* bout = (const float*)d_in[10];
  char* ws = (char*)d_ws;

  u16* WH0 = (u16*)(ws + OFF_WH0);
  const u16* WI1 = (const u16*)(ws + OFF_WI1);
  const u16* WH1 = (const u16*)(ws + OFF_WH1);
  const u16* WI0 = (const u16*)(ws + OFF_WI0);
  u16 *H0HI = (u16*)(ws + OFF_H0HI), *H0LO = (u16*)(ws + OFF_H0LO);
  u16 *H1HI = (u16*)(ws + OFF_H1HI), *H1LO = (u16*)(ws + OFF_H1LO);

  prep_w  <<<1152, 256, 0, stream>>>(Whh0, Wih1, Whh1, WH0);
  prep_wi0<<<  24, 256, 0, stream>>>(Wih0, (u16*)(ws + OFF_WI0));
  zero_ws <<<2048, 256, 0, stream>>>(ws);

  for (int s = 0; s < Tn; ++s){
    int rp = s & 1, wp = rp ^ 1;
    gru_step<1><<<512, 256, 0, stream>>>(
        WI0, (const u16*)WH0,
        x + (size_t)s*Bn*Fn,
        nullptr, nullptr,
        H0HI + (size_t)rp*1048576, H0LO + (size_t)rp*1048576,
        bih0, bhh0,
        H0HI + (size_t)wp*1048576, H0LO + (size_t)wp*1048576);
    gru_step<0><<<512, 256, 0, stream>>>(
        WI1, WH1,
        nullptr,
        H0HI + (size_t)wp*1048576, H0LO + (size_t)wp*1048576,
        H1HI + (size_t)rp*1048576, H1LO + (size_t)rp*1048576,
        bih1, bhh1,
        H1HI + (size_t)wp*1048576, H1LO + (size_t)wp*1048576);
  }

  outproj<<<2048, 64, 0, stream>>>(
      H1HI, H1LO, Wout, bout, (float*)d_out);
}

// Round 3
// 17923.047 us; speedup vs baseline: 4.4778x; 1.1824x over previous
//
#include <hip/hip_runtime.h>

#define DI __device__ __forceinline__

typedef __bf16  bf16x8 __attribute__((ext_vector_type(8)));
typedef float   f32x4  __attribute__((ext_vector_type(4)));
typedef unsigned short u16;
typedef unsigned int   u32;

DI u16 f2bf(float f){ u32 u = __float_as_uint(f); u32 r = 0x7fffu + ((u>>16)&1u); return (u16)((u + r) >> 16); }
DI float bf2f(u16 h){ return __uint_as_float(((u32)h)<<16); }

union U16x8 { u16 u[8]; uint4 v; };
union AB    { uint4 u; bf16x8 b; };

#define MFMA(a,b,c) __builtin_amdgcn_mfma_f32_16x16x32_bf16((a),(b),(c),0,0,0)

// async global->LDS, 16B per lane. LDS dest = wave-uniform base (+lane*16 by HW).
DI void gload16(const void* g, void* l){
  __builtin_amdgcn_global_load_lds((const __attribute__((address_space(1))) u32*)g,
                                   (__attribute__((address_space(3))) u32*)l, 16, 0, 0);
}
// global->VGPR 16B load, NOT tracked by compiler's waitcnt (we wait manually).
DI void aload(uint4& d, const void* p){
  asm volatile("global_load_dwordx4 %0, %1, off" : "=&v"(d) : "v"(p) : "memory");
}
template<int N> DI void wait_vmcnt(){ asm volatile("s_waitcnt vmcnt(%0)" :: "n"(N) : "memory"); }
DI void vwait(int n){
  switch(n){
    case 0:  wait_vmcnt<0>();  break;
    case 4:  wait_vmcnt<4>();  break;
    case 8:  wait_vmcnt<8>();  break;
    case 9:  wait_vmcnt<9>();  break;
    case 10: wait_vmcnt<10>(); break;
    default: wait_vmcnt<12>(); break;
  }
}

// ---- problem constants
#define Tn 512
#define Bn 2048
#define Fn 16
#define Hn 512
#define NK32 16   // 512/32 k-subtiles

// ---- workspace layout (bytes)
#define OFF_WH0  0ull
#define OFF_WI1  3145728ull
#define OFF_WH1  6291456ull
#define OFF_WI0  9437184ull
#define OFF_H0HI 9633792ull
#define OFF_H0LO 13828096ull
#define OFF_H1HI 18022400ull
#define OFF_H1LO 22216704ull
// total 26411008 bytes

// =====================================================================
// Prep: fp32 [3H x K] weights -> frag-linear bf16 hi/lo subtile pairs.
// Subtile (16j x 32k) = 64 lanes x 16B, lane = (j&15) + ((k>>3)&3)*16,
// byte-in-lane = (k&7)*2.  Pair = {hi 1KB, lo 1KB}.
// pairidx = (g*32 + (j>>4))*NK + k32
// =====================================================================
__global__ __launch_bounds__(256) void prep_w(const float* __restrict__ w0,
                                              const float* __restrict__ w1,
                                              const float* __restrict__ w2,
                                              u16* __restrict__ dst){
  int tid = blockIdx.x*256 + threadIdx.x;        // 294912 total
  int p = tid / 98304, rem = tid % 98304;        // part: 0=WH0 1=WI1 2=WH1
  int g = rem / 32768, rem2 = rem % 32768;
  int j = rem2 / 64,   k8 = rem2 % 64;           // k = k8*8
  const float* src = (p==0) ? w0 : ((p==1) ? w1 : w2);
  const float* s = src + (size_t)(g*Hn + j)*Hn + k8*8;
  U16x8 hi, lo;
#pragma unroll
  for (int i=0;i<8;++i){ float v = s[i]; u16 h = f2bf(v); hi.u[i]=h; lo.u[i]=f2bf(v - bf2f(h)); }
  size_t pairidx = (size_t)(g*32 + (j>>4))*16 + (k8>>2);
  u16* d = dst + (size_t)p*1572864 + pairidx*1024 + (size_t)((j&15) + (k8&3)*16)*8;
  *(uint4*)d = hi.v;
  *(uint4*)(d + 512) = lo.v;
}

// W_ih0: [3H x 16] padded to K=32 (upper k zeros), NK=1
__global__ __launch_bounds__(256) void prep_wi0(const float* __restrict__ w,
                                                u16* __restrict__ dst){
  int tid = blockIdx.x*256 + threadIdx.x;        // 6144 total
  int g = tid / 2048, j = (tid % 2048) >> 2, k8 = tid & 3;
  U16x8 hi, lo;
  if (k8 < 2){
    const float* s = w + (size_t)(g*Hn + j)*Fn + k8*8;
#pragma unroll
    for (int i=0;i<8;++i){ float v = s[i]; u16 h = f2bf(v); hi.u[i]=h; lo.u[i]=f2bf(v - bf2f(h)); }
  } else {
#pragma unroll
    for (int i=0;i<8;++i){ hi.u[i]=0; lo.u[i]=0; }
  }
  size_t pairidx = (size_t)(g*32 + (j>>4));
  u16* d = dst + pairidx*1024 + (size_t)((j&15) + k8*16)*8;
  *(uint4*)d = hi.v;
  *(uint4*)(d + 512) = lo.v;
}

// zero parity-0 hi/lo state buffers
__global__ __launch_bounds__(256) void zero_ws(char* __restrict__ ws){
  int tid = blockIdx.x*256 + threadIdx.x;        // 524288 x 16B
  uint4 z = {0u,0u,0u,0u};
  int region = tid >> 17;                        // 131072 x 16B = 2MB each
  int off = tid & 131071;
  size_t base = (region==0) ? OFF_H0HI : (region==1) ? OFF_H0LO
              : (region==2) ? OFF_H1HI : OFF_H1LO;
  *(uint4*)(ws + base + (size_t)off*16) = z;
}

// =====================================================================
// Fused GEMM + GRU-cell step kernel, mt-pinned to XCDs.
// Grid 512: xcd = bid&7 owns mt in {2*xcd... }: mt = (bid&7)*2 + ((bid>>3)&1),
// jt = bid>>4. h-state (A) is XCD-local; W streams from L3 (read-only).
// Block 256 (4 waves), wave w owns rows [w*32, w*32+32).
// A (h hi/lo) -> registers via asm global_load_dwordx4, depth-3 prefetch.
// W -> LDS via global_load_lds, 6 slots, depth-5 prefetch, counted vmcnt.
// acc[m][0]=i_r+h_r  acc[m][1]=i_z+h_z  acc[m][2]=i_n  acc[m][3]=h_n
// LDS: W 6 x 6KB = 36864 + X 8192 = 45056 B -> 2 blocks/CU.
// =====================================================================
template<int IS_L0>
__global__ __launch_bounds__(256, 2) void gru_step(
    const u16* __restrict__ Wi, const u16* __restrict__ Wh,
    const float* __restrict__ xsrc,
    const u16* __restrict__ Ai_hi, const u16* __restrict__ Ai_lo,
    const u16* __restrict__ Ah_hi, const u16* __restrict__ Ah_lo,
    const float* __restrict__ b_ih, const float* __restrict__ b_hh,
    u16* __restrict__ hout_hi, u16* __restrict__ hout_lo)
{
  constexpr int NI = IS_L0 ? 1 : 16;     // i-stream K-steps
  constexpr int NT = IS_L0 ? 17 : 32;    // total K-steps
  __shared__ __align__(16) char smem[45056];
  const int tid  = threadIdx.x;
  const int lane = tid & 63, wv = tid >> 6;
  const int bid = blockIdx.x;
  const int mt = (bid & 7)*2 + ((bid >> 3) & 1);
  const int jt = bid >> 4;

  f32x4 acc[2][4];
#pragma unroll
  for (int m=0;m<2;++m)
#pragma unroll
    for (int o=0;o<4;++o){ f32x4 z = {0.f,0.f,0.f,0.f}; acc[m][o] = z; }

  // ---- L0: prestage x tile (K=16 real, padded to 32) as bf16 frag-linear
  if (IS_L0){
    int b_loc = tid >> 1, kh = tid & 1;
    const float* xs = xsrc + (size_t)(mt*128 + b_loc)*Fn + kh*8;
    U16x8 u;
#pragma unroll
    for (int i=0;i<8;++i) u.u[i] = f2bf(xs[i]);
    char* dst = smem + 36864 + (b_loc>>4)*1024 + (size_t)((b_loc&15) + kh*16)*16;
    *(uint4*)dst = u.v;
    uint4 z = {0u,0u,0u,0u};
    *(uint4*)(dst + 512) = z;      // k 16..31 zero pad
  }

  uint4 areg[16];                  // 4 sets x {m0hi,m0lo,m1hi,m1lo}

  // W stage: wave0:{0,1} wave1:{2,3} wave2:{4} wave3:{5}; task=g*2+hl
  auto issueW = [&](int s){
    char* buf = smem + (s % 6)*6144;
    bool ish = (s >= NI);
    const u16* w; int nk, k32w;
    if (IS_L0 && !ish){ w = Wi; nk = 1; k32w = 0; }
    else { w = ish ? Wh : Wi; nk = NK32; k32w = ish ? (s - NI) : s; }
    int ntask = (wv < 2) ? 2 : 1;
    int tbase = (wv < 2) ? wv*2 : (2 + wv);
    for (int ii=0; ii<ntask; ++ii){
      int task = tbase + ii, g = task >> 1, hl = task & 1;
      size_t go = ((size_t)((g*32 + jt)*nk + k32w))*1024 + (size_t)hl*512 + (size_t)lane*8;
      gload16(w + go, buf + task*1024);
    }
  };

  auto issueA = [&](int s, uint4* dst){
    bool ish = (s >= NI);
    if (IS_L0 && !ish) return;     // step 0 uses x from LDS
    int k32 = ish ? (s - NI) : s;
    const u16* ahi = ish ? Ah_hi : Ai_hi;
    const u16* alo = ish ? Ah_lo : Ai_lo;
#pragma unroll
    for (int m=0;m<2;++m){
      size_t go = ((size_t)((mt*8 + wv*2 + m)*NK32 + k32))*512 + (size_t)lane*8;
      aload(dst[m*2],   ahi + go);
      aload(dst[m*2+1], alo + go);
    }
  };

  auto compute = [&](int t, const uint4* ar){
    const char* buf = smem + (t % 6)*6144;
    bf16x8 w[3][2];
#pragma unroll
    for (int g=0; g<3; ++g)
#pragma unroll
      for (int hl=0; hl<2; ++hl)
        w[g][hl] = *(const bf16x8*)(buf + (g*2+hl)*1024 + lane*16);
    bool ish = (t >= NI);
    if (IS_L0 && t==0){
#pragma unroll
      for (int m=0;m<2;++m){
        bf16x8 ax = *(const bf16x8*)(smem + 36864 + (wv*2+m)*1024 + lane*16);
        acc[m][0] = MFMA(ax, w[0][0], acc[m][0]); acc[m][0] = MFMA(ax, w[0][1], acc[m][0]);
        acc[m][1] = MFMA(ax, w[1][0], acc[m][1]); acc[m][1] = MFMA(ax, w[1][1], acc[m][1]);
        acc[m][2] = MFMA(ax, w[2][0], acc[m][2]); acc[m][2] = MFMA(ax, w[2][1], acc[m][2]);
      }
    } else {
#pragma unroll
      for (int m=0;m<2;++m){
        AB cah, cal; cah.u = ar[m*2]; cal.u = ar[m*2+1];
        bf16x8 ah = cah.b, al = cal.b;
        acc[m][0] = MFMA(ah, w[0][0], acc[m][0]);
        acc[m][0] = MFMA(ah, w[0][1], acc[m][0]);
        acc[m][0] = MFMA(al, w[0][0], acc[m][0]);
        acc[m][1] = MFMA(ah, w[1][0], acc[m][1]);
        acc[m][1] = MFMA(ah, w[1][1], acc[m][1]);
        acc[m][1] = MFMA(al, w[1][0], acc[m][1]);
        if (!ish){
          acc[m][2] = MFMA(ah, w[2][0], acc[m][2]);
          acc[m][2] = MFMA(ah, w[2][1], acc[m][2]);
          acc[m][2] = MFMA(al, w[2][0], acc[m][2]);
        } else {
          acc[m][3] = MFMA(ah, w[2][0], acc[m][3]);
          acc[m][3] = MFMA(ah, w[2][1], acc[m][3]);
          acc[m][3] = MFMA(al, w[2][0], acc[m][3]);
        }
      }
    }
  };

  // ---- prologue: W depth-5, A depth-3 (issue order matters for vmcnt FIFO)
  issueW(0); issueW(1); issueW(2); issueW(3); issueW(4);
  issueA(0, &areg[0]); issueA(1, &areg[4]); issueA(2, &areg[8]);
  asm volatile("s_waitcnt lgkmcnt(0)" ::: "memory");   // x prestage drained (L0)

  // ---- main loop: wait(counted) -> barrier -> compute(t) -> issue(t+5 W, t+3 A)
#pragma unroll
  for (int t=0; t<NT; ++t){
    int d = NT-1-t;
    int lv01, lv23;
    if      (t==0){ lv01=8;  lv23=8; }
    else if (t==1){ lv01=10; lv23=9; }
    else if (d>=4){ lv01=12; lv23=10; }
    else if (d==3){ lv01=10; lv23=9; }
    else if (d==2){ lv01=8;  lv23=8; }
    else if (d==1){ lv01=4;  lv23=4; }
    else          { lv01=0;  lv23=0; }
    if (wv < 2) vwait(lv01); else vwait(lv23);
    __builtin_amdgcn_sched_barrier(0);
    __builtin_amdgcn_s_barrier();
    compute(t, &areg[(t&3)*4]);
    if (t+5 < NT) issueW(t+5);
    if (t+3 < NT) issueA(t+3, &areg[((t+3)&3)*4]);
  }

  // ---- GRU epilogue (C-fragment map: col=lane&15, row=(lane>>4)*4+r)
  const int col = lane & 15, rg = lane >> 4;
  const int j = jt*16 + col;
  const float bir = b_ih[j], biz = b_ih[Hn + j], bin = b_ih[2*Hn + j];
  const float bhr = b_hh[j], bhz = b_hh[Hn + j], bhn = b_hh[2*Hn + j];
#pragma unroll
  for (int m=0;m<2;++m){
    int brow = mt*128 + wv*32 + m*16 + rg*4;
#pragma unroll
    for (int r=0;r<4;++r){
      int b = brow + r;
      float pr  = acc[m][0][r] + bir + bhr;
      float pz  = acc[m][1][r] + biz + bhz;
      float pin = acc[m][2][r] + bin;
      float phn = acc[m][3][r] + bhn;
      float rgt = 1.f/(1.f + __expf(-pr));
      float zgt = 1.f/(1.f + __expf(-pz));
      float e2  = __expf(2.f*(pin + rgt*phn));
      float nn  = 1.f - 2.f/(e2 + 1.f);           // tanh, overflow-safe
      size_t fo = ((size_t)(b>>4)*NK32 + (j>>5))*512 + (size_t)((b&15) + ((j>>3)&3)*16)*8 + (j&7);
      float hv  = bf2f(Ah_hi[fo]) + bf2f(Ah_lo[fo]);   // h_prev reconstructed
      float hnv = (1.f - zgt)*nn + zgt*hv;
      u16 hi = f2bf(hnv);
      u16 lo = f2bf(hnv - bf2f(hi));
      hout_hi[fo] = hi; hout_lo[fo] = lo;
    }
  }
}

// final projection: out[b][o] = h1[b,:] . Wout[o,:] + bout[o]
__global__ __launch_bounds__(64) void outproj(const u16* __restrict__ h1hi,
                                              const u16* __restrict__ h1lo,
                                              const float* __restrict__ Wout,
                                              const float* __restrict__ bout,
                                              float* __restrict__ out){
  int b = blockIdx.x, l = threadIdx.x;
  float a[8] = {0.f,0.f,0.f,0.f,0.f,0.f,0.f,0.f};
  for (int jj = l; jj < Hn; jj += 64){
    size_t fo = ((size_t)(b>>4)*NK32 + (jj>>5))*512 + (size_t)((b&15) + ((jj>>3)&3)*16)*8 + (jj&7);
    float hv = bf2f(h1hi[fo]) + bf2f(h1lo[fo]);
#pragma unroll
    for (int o=0;o<8;++o) a[o] += hv * Wout[o*Hn + jj];
  }
#pragma unroll
  for (int o=0;o<8;++o){
#pragma unroll
    for (int off=32; off; off>>=1) a[o] += __shfl_xor(a[o], off);
  }
  if (l == 0){
#pragma unroll
    for (int o=0;o<8;++o) out[b*8+o] = a[o] + bout[o];
  }
}

extern "C" void kernel_launch(void* const* d_in, const int* in_sizes, int n_in,
                              void* d_out, int out_size, void* d_ws, size_t ws_size,
                              hipStream_t stream){
  (void)in_sizes; (void)n_in; (void)out_size; (void)ws_size;
  const float* x    = (const float*)d_in[0];
  const float* Wih0 = (const float*)d_in[1];
  const float* Whh0 = (const float*)d_in[2];
  const float* bih0 = (const float*)d_in[3];
  const float* bhh0 = (const float*)d_in[4];
  const float* Wih1 = (const float*)d_in[5];
  const float* Whh1 = (const float*)d_in[6];
  const float* bih1 = (const float*)d_in[7];
  const float* bhh1 = (const float*)d_in[8];
  const float* Wout = (const float*)d_in[9];
  const float* bout = (const float*)d_in[10];
  char* ws = (char*)d_ws;

  u16* WH0 = (u16*)(ws + OFF_WH0);
  const u16* WI1 = (const u16*)(ws + OFF_WI1);
  const u16* WH1 = (const u16*)(ws + OFF_WH1);
  const u16* WI0 = (const u16*)(ws + OFF_WI0);
  u16 *H0HI = (u16*)(ws + OFF_H0HI), *H0LO = (u16*)(ws + OFF_H0LO);
  u16 *H1HI = (u16*)(ws + OFF_H1HI), *H1LO = (u16*)(ws + OFF_H1LO);

  prep_w  <<<1152, 256, 0, stream>>>(Whh0, Wih1, Whh1, WH0);
  prep_wi0<<<  24, 256, 0, stream>>>(Wih0, (u16*)(ws + OFF_WI0));
  zero_ws <<<2048, 256, 0, stream>>>(ws);

  for (int s = 0; s < Tn; ++s){
    int rp = s & 1, wp = rp ^ 1;
    gru_step<1><<<512, 256, 0, stream>>>(
        WI0, (const u16*)WH0,
        x + (size_t)s*Bn*Fn,
        nullptr, nullptr,
        H0HI + (size_t)rp*1048576, H0LO + (size_t)rp*1048576,
        bih0, bhh0,
        H0HI + (size_t)wp*1048576, H0LO + (size_t)wp*1048576);
    gru_step<0><<<512, 256, 0, stream>>>(
        WI1, WH1,
        nullptr,
        H0HI + (size_t)wp*1048576, H0LO + (size_t)wp*1048576,
        H1HI + (size_t)rp*1048576, H1LO + (size_t)rp*1048576,
        bih1, bhh1,
        H1HI + (size_t)wp*1048576, H1LO + (size_t)wp*1048576);
  }

  outproj<<<2048, 64, 0, stream>>>(
      H1HI, H1LO, Wout, bout, (float*)d_out);
}